// Round 15
// baseline (351.981 us; speedup 1.0000x reference)
//
#include <hip/hip_runtime.h>
#include <hip/hip_bf16.h>
#include <math.h>

#define LEN 128
#define TOTAL 349504
#define NCONSTR 8
#define BONUS 1000.0f
#define BUFQ4 1088              // staging buffer: 17 chunks x 256 floats = 4352 floats

typedef __attribute__((address_space(1))) const unsigned int guint;
typedef __attribute__((address_space(3))) unsigned int luint;

template<int N> __device__ __forceinline__ void wait_vm(){
    static_assert(N >= 0 && N <= 17, "vmcnt range");
    if constexpr (N==0)  asm volatile("s_waitcnt vmcnt(0)":::"memory");
    else if constexpr (N==1)  asm volatile("s_waitcnt vmcnt(1)":::"memory");
    else if constexpr (N==4)  asm volatile("s_waitcnt vmcnt(4)":::"memory");
    else if constexpr (N==8)  asm volatile("s_waitcnt vmcnt(8)":::"memory");
    else if constexpr (N==13) asm volatile("s_waitcnt vmcnt(13)":::"memory");
    else if constexpr (N==16) asm volatile("s_waitcnt vmcnt(16)":::"memory");
    else asm volatile("s_waitcnt vmcnt(17)":::"memory");
    __builtin_amdgcn_sched_barrier(0);
}

__device__ __forceinline__ float dpp_xor1_max(float v){
    int r = __builtin_amdgcn_update_dpp(0, __float_as_int(v), 0xB1, 0xF, 0xF, true);
    return fmaxf(v, __int_as_float(r));
}
__device__ __forceinline__ float dpp_xor2_max(float v){
    int r = __builtin_amdgcn_update_dpp(0, __float_as_int(v), 0x4E, 0xF, 0xF, true);
    return fmaxf(v, __int_as_float(r));
}

__device__ __forceinline__ bool chit(int q, const int4 c0, const int4 c1){
    return (q==c0.x)|(q==c0.y)|(q==c0.z)|(q==c0.w)|
           (q==c1.x)|(q==c1.y)|(q==c1.z)|(q==c1.w);
}

// Stage [soff, soff+LN) of g linearly into dst (LDS) via global_load_lds
// dwordx4: 64 lanes x 16B = 1024B/instr. Head-aligned to 4 floats; consumer
// adds pad = soff & 3. cnt <= 17.
__device__ __forceinline__ void stage(const float* __restrict__ g, int soff,
                                      int LN, float* dst, int lane){
    const int a0 = soff & ~3;
    const int cnt = (soff - a0 + LN + 255) >> 8;
    const float* s = g + a0 + (lane << 2);
    #pragma unroll 1
    for (int k = 0; k < cnt; ++k){
        __builtin_amdgcn_global_load_lds((guint*)(s + (k << 8)),
                                         (luint*)(dst + (k << 8)), 16, 0, 0);
    }
}

// T=1 level: lane owns cell pos=lane (and pos+64 when CPL=2). Serial loop
// over n; chart reads lane-stride-1 (conflict-free); x from staged LDS.
// No barriers: wave-internal DS ordering guarantees chart RAW.
template<int CPL, int WK>
__device__ __forceinline__ void levT1(const int l, int& soff, int& offN1, int& sQ,
    const float* __restrict__ g, float* __restrict__ ch,
    float* __restrict__ bufp, const int4 cc0, const int4 cc1,
    const float kb, const int lane)
{
    const int N = l, L = LEN - l;
    wait_vm<WK>();
    const int pad = soff & 3;
    const float* xs = bufp + pad;
    const int lc1 = (lane < L - 1) ? lane : (L - 1);
    const float* xp1 = xs + lc1 * N;
    const float* xp2 = xs;
    if constexpr (CPL == 2){
        const int lc2 = (lane + 64 < L - 1) ? (lane + 64) : (L - 1);
        xp2 = xs + lc2 * N;
    }
    int a = lane;                    // OFF(0)+lane
    int r = offN1 + lane + 1;        // OFF(N-1)+lane+1
    int da = 128, dr = N - 129;
    float acc1 = -INFINITY, acc2 = -INFINITY;
    #pragma unroll 4
    for (int n = 0; n < N; ++n){
        const float lv1 = ch[a], rv1 = ch[r];
        const float x1 = xp1[n];
        acc1 = fmaxf(acc1, lv1 + rv1 + x1);
        if constexpr (CPL == 2){
            const float lv2 = ch[a + 64], rv2 = ch[r + 64];
            const float x2 = xp2[n];
            acc2 = fmaxf(acc2, lv2 + rv2 + x2);
        }
        a += da; --da;
        r += dr; --dr;
    }
    const int q1 = sQ + lane;
    if ((CPL == 2) || (lane < L))
        ch[q1] = acc1 + (chit(q1, cc0, cc1) ? kb : 0.f);
    if constexpr (CPL == 2){
        if (lane + 64 < L){
            const int q2 = q1 + 64;
            ch[q2] = acc2 + (chit(q2, cc0, cc1) ? kb : 0.f);
        }
    }
    const int soffn = soff + L * N;
    if (l + 2 <= 127)
        stage(g, soffn + (L - 1) * (N + 1), (L - 2) * (N + 2), bufp, lane);
    soff = soffn;
    offN1 = sQ;
    sQ += 128 - l;
}

// T=2^LG lanes per cell (high levels). Reduce via DPP/shfl within the wave.
template<int LG, int WK>
__device__ __forceinline__ void levTk(const int l, int& soff, int& offN1, int& sQ,
    const float* __restrict__ g, float* __restrict__ ch,
    float* __restrict__ bufp, const int4 cc0, const int4 cc1,
    const float kb, const int lane)
{
    const int N = l, L = LEN - l;
    constexpr int T = 1 << LG;
    wait_vm<WK>();
    const int pad = soff & 3;
    const int pos = lane >> LG, sub = lane & (T - 1);
    const int posc = (pos < L - 1) ? pos : (L - 1);
    const float* xp = bufp + pad + posc * N;
    const int m0 = N - 1 - sub;
    int a = ((sub * (257 - sub)) >> 1) + posc;
    int r = ((m0 * (257 - m0)) >> 1) + posc + sub + 1;
    int da = T * 128 - T * sub - (T * (T - 1)) / 2;
    int dr = T * m0 - (T * 129 + (T * (T - 1)) / 2) + T;
    float acc = -INFINITY;
    #pragma unroll 4
    for (int n0 = 0; n0 < N; n0 += T){
        const int n = n0 + sub;
        const float lv = ch[a], rv = ch[r];
        float x = xp[n0 + sub];
        x = (n < N) ? x : -INFINITY;
        acc = fmaxf(acc, lv + rv + x);
        a += da; da -= T * T;
        r += dr; dr -= T * T;
    }
    if constexpr (LG >= 1) acc = dpp_xor1_max(acc);
    if constexpr (LG >= 2) acc = dpp_xor2_max(acc);
    if constexpr (LG >= 3) acc = fmaxf(acc, __shfl_xor(acc, 4));
    if (sub == 0 && pos < L){
        const int q = sQ + pos;
        ch[q] = acc + (chit(q, cc0, cc1) ? kb : 0.f);
    }
    const int soffn = soff + L * N;
    if (l + 2 <= 127)
        stage(g, soffn + (L - 1) * (N + 1), (L - 2) * (N + 2), bufp, lane);
    soff = soffn;
    offN1 = sQ;
    sQ += 128 - l;
}

__global__ __launch_bounds__(128)
void cky_wave_kernel(const float* __restrict__ scores,
                     const int* __restrict__ cpos,
                     float* __restrict__ ws)
{
    __shared__ float  chA[8256], chB[8256];
    __shared__ float4 bufs[2][2][BUFQ4];     // [wave][parity]

    const int b    = blockIdx.x;
    const int tid  = threadIdx.x;
    const int w    = tid >> 6;
    const int lane = tid & 63;
    float* __restrict__ ch = w ? chB : chA;
    const float kb = w ? BONUS : 0.f;
    const float* __restrict__ g = scores + (size_t)b * TOTAL;

    const int4* __restrict__ cp4 = (const int4*)(cpos + b * NCONSTR);
    const int4 cc0 = cp4[0];
    const int4 cc1 = cp4[1];

    // zero row 0 of own chart (wave-internal order suffices; no barrier)
    ch[lane] = 0.f;
    ch[lane + 64] = 0.f;

    // prologue: stage level 1 into parity-1 buffer, level 2 into parity-0
    stage(g, 0,   127, (float*)&bufs[w][1][0], lane);
    stage(g, 127, 252, (float*)&bufs[w][0][0], lane);

    int soff = 0, offN1 = 0, sQ = 128;   // SOFF(l), OFF(l-1), OFF(l) at l=1
    int l = 1;
    #pragma unroll 1
    for (; l <= 15; ++l)  levT1<2,1> (l, soff, offN1, sQ, g, ch, (float*)&bufs[w][l&1][0], cc0, cc1, kb, lane);
    #pragma unroll 1
    for (; l <= 31; ++l)  levT1<2,8> (l, soff, offN1, sQ, g, ch, (float*)&bufs[w][l&1][0], cc0, cc1, kb, lane);
    #pragma unroll 1
    for (; l <= 47; ++l)  levT1<2,13>(l, soff, offN1, sQ, g, ch, (float*)&bufs[w][l&1][0], cc0, cc1, kb, lane);
    #pragma unroll 1
    for (; l <= 63; ++l)  levT1<2,16>(l, soff, offN1, sQ, g, ch, (float*)&bufs[w][l&1][0], cc0, cc1, kb, lane);
    #pragma unroll 1
    for (; l <= 95; ++l)  levT1<1,13>(l, soff, offN1, sQ, g, ch, (float*)&bufs[w][l&1][0], cc0, cc1, kb, lane);
    #pragma unroll 1
    for (; l <= 111; ++l) levTk<1,8> (l, soff, offN1, sQ, g, ch, (float*)&bufs[w][l&1][0], cc0, cc1, kb, lane);
    #pragma unroll 1
    for (; l <= 119; ++l) levTk<2,4> (l, soff, offN1, sQ, g, ch, (float*)&bufs[w][l&1][0], cc0, cc1, kb, lane);
    #pragma unroll 1
    for (; l <= 126; ++l) levTk<3,1> (l, soff, offN1, sQ, g, ch, (float*)&bufs[w][l&1][0], cc0, cc1, kb, lane);
    levTk<3,0>(127, soff, offN1, sQ, g, ch, (float*)&bufs[w][1][0], cc0, cc1, kb, lane);

    __syncthreads();   // the ONLY barrier: join pred/constr waves for the hinge

    if (tid == 0){
        const float pred   = chA[8255];
        const float constr = chB[8255] - BONUS * NCONSTR;
        const float diff   = pred - constr;
        const float mask   = (fabsf(diff) >= 0.001f) ? 1.f : 0.f;
        const float hinge  = fmaxf(1.0f + diff, 0.f) * mask;
        atomicAdd(ws + 0, hinge);
        atomicAdd(ws + 1, mask);
    }
}

__global__ void final_kernel(const float* __restrict__ ws, float* __restrict__ out){
    const float h = ws[0];
    const float m = ws[1];
    out[0] = (m > 0.1f) ? (h / fmaxf(m, 1.f)) : h;
}

extern "C" void kernel_launch(void* const* d_in, const int* in_sizes, int n_in,
                              void* d_out, int out_size, void* d_ws, size_t ws_size,
                              hipStream_t stream) {
    const float* scores = (const float*)d_in[0];
    const int*   cpos   = (const int*)d_in[1];
    float* out = (float*)d_out;
    float* ws  = (float*)d_ws;

    hipMemsetAsync(ws, 0, 2 * sizeof(float), stream);
    cky_wave_kernel<<<dim3(256), dim3(128), 0, stream>>>(scores, cpos, ws);
    final_kernel<<<dim3(1), dim3(1), 0, stream>>>(ws, out);
}

// Round 16
// 148.681 us; speedup vs baseline: 2.3674x; 2.3674x over previous
//
#include <hip/hip_runtime.h>
#include <hip/hip_bf16.h>
#include <math.h>

#define LEN 128
#define NCELLS 8256          // LEN*(LEN+1)/2
#define TOTAL 349504         // sum_{l=1}^{127} (128-l)*l
#define NCONSTR 8
#define BONUS 1000.0f
#define NT 512
#define SBUF 4480            // per-parity score buffer (max 4096 + pad 258 + tail 64)

typedef __attribute__((address_space(1))) const unsigned int guint;
typedef __attribute__((address_space(3))) unsigned int luint;

// lgkm-only barrier (chart ordering); staging drains are explicit per level.
__device__ __forceinline__ void level_barrier() {
    __builtin_amdgcn_sched_barrier(0);
    asm volatile("s_waitcnt lgkmcnt(0)\n\ts_barrier" ::: "memory");
    __builtin_amdgcn_sched_barrier(0);
}
// Full drain barrier: staging (vmcnt) + LDS (lgkm) complete, then sync.
__device__ __forceinline__ void drain_barrier() {
    __builtin_amdgcn_sched_barrier(0);
    asm volatile("s_waitcnt vmcnt(0) lgkmcnt(0)\n\ts_barrier" ::: "memory");
    __builtin_amdgcn_sched_barrier(0);
}

__device__ __forceinline__ float dpp_xor1_max(float v) {
    int r = __builtin_amdgcn_update_dpp(0, __float_as_int(v), 0xB1, 0xF, 0xF, true);
    return fmaxf(v, __int_as_float(r));
}
__device__ __forceinline__ float dpp_xor2_max(float v) {
    int r = __builtin_amdgcn_update_dpp(0, __float_as_int(v), 0x4E, 0xF, 0xF, true);
    return fmaxf(v, __int_as_float(r));
}
template<int LG>
__device__ __forceinline__ void redmax2(float& a, float& b) {
    #pragma unroll
    for (int mm = (1 << LG) >> 1; mm >= 4; mm >>= 1) {
        a = fmaxf(a, __shfl_xor(a, mm));
        b = fmaxf(b, __shfl_xor(b, mm));
    }
    if constexpr (LG >= 2) { a = dpp_xor2_max(a); b = dpp_xor2_max(b); }
    if constexpr (LG >= 1) { a = dpp_xor1_max(a); b = dpp_xor1_max(b); }
}

// Coalesced staging of score region [soff, soff+LN) into LDS dst via
// global_load_lds dwordx4 (wave-uniform LDS base + lane*16B). Chunks of
// 1024B round-robin across the 8 waves. astart clamps the final chunks
// inside the batch's score array; consumer adds pad = soff - astart.
__device__ __forceinline__ void stage(const float* __restrict__ g, int soff,
                                      int LN, float* __restrict__ dst, int tid)
{
    const int chunks = (LN + 258) >> 8;
    int astart = soff & ~3;
    const int amax = TOTAL - (chunks << 8);
    astart = (astart < amax) ? astart : amax;
    const int w = tid >> 6;
    const float* src = g + astart + ((tid & 63) << 2);
    #pragma unroll 1
    for (int c = w; c < chunks; c += 8) {
        __builtin_amdgcn_global_load_lds((guint*)(src + (c << 8)),
                                         (luint*)(dst + (c << 8)), 16, 0, 0);
    }
}

// One CKY level (r4-verified body; scores from LDS instead of registers).
// Phase 1: batch-issue 2*JM chart ds_read_b64 + JM score ds_read_b32;
// phase 2: consume. Staging for level+1 is issued FIRST (HBM latency hides
// under this level's compute); end-of-level barrier drains vmcnt+lgkm.
template<int LG, int JM, bool STG>
__device__ __forceinline__ void lstep(const int level, int& soff,
        const float* __restrict__ g, float2* __restrict__ chart,
        const float* __restrict__ sbc, float* __restrict__ sbn, const int tid)
{
    const int N = level;
    const int L = LEN - level;
    constexpr int T = 1 << LG;
    const int pos = tid >> LG;
    const int sub = tid & (T - 1);
    const int soff_n = soff + L * N;

    // ---- issue coalesced staging of next level's scores ----
    if constexpr (STG) {
        stage(g, soff_n, (L - 1) * (N + 1), sbn, tid);
    }

    // ---- current level's pad (recomputed; matches stage() of last level) ----
    int pad;
    {
        const int LN = L * N;
        const int chk = (LN + 258) >> 8;
        int ast = soff & ~3;
        const int am = TOTAL - (chk << 8);
        ast = (ast < am) ? ast : am;
        pad = soff - ast;
    }

    // ---- compute this level ----
    float bp = -INFINITY, bc = -INFINITY;
    if (pos < L) {
        const int jml = (N - sub + T - 1) >> LG;   // per-lane valid trip count
        const float* xrow = sbc + pad + pos * N + sub;
        float2 lv[JM], rv[JM];
        float  xs[JM];
        #pragma unroll
        for (int j = 0; j < JM; j++) {
            const int n = sub + j * T;
            const int m = level - 1 - n;
            const bool v = (j < jml);
            const int l_idx = ((n * (257 - n)) >> 1) + pos;
            int r_idx = ((m * (257 - m)) >> 1) + pos + n + 1;
            r_idx = v ? r_idx : 0;
            lv[j] = chart[l_idx];
            rv[j] = chart[r_idx];
            const float xl = xrow[j * T];          // in-bounds even when !v
            xs[j] = v ? xl : -INFINITY;
        }
        #pragma unroll
        for (int j = 0; j < JM; j++) {
            bp = fmaxf(bp, lv[j].x + rv[j].x + xs[j]);
            bc = fmaxf(bc, lv[j].y + rv[j].y + xs[j]);
        }
    }
    redmax2<LG>(bp, bc);
    if (pos < L && sub == 0) {
        const int q = ((level * (257 - level)) >> 1) + pos;
        float2 c = chart[q];
        c.x += bp;
        c.y += bc;
        chart[q] = c;
    }
    drain_barrier();
    soff = soff_n;
}

// 4 levels at TPP=4, JM=K exactly (levels 4K-3..4K); parity alternates sbuf.
template<int K>
__device__ __forceinline__ void seg4(int& soff, const float* __restrict__ g,
        float2* __restrict__ chart, float* __restrict__ sb0,
        float* __restrict__ sb1, const int tid)
{
    const int l0 = 4 * K - 3;
    #pragma unroll 1
    for (int l = l0; l < l0 + 4; l += 2) {
        lstep<2, K, true>(l,     soff, g, chart, sb1, sb0, tid);   // odd level
        lstep<2, K, true>(l + 1, soff, g, chart, sb0, sb1, tid);   // even level
    }
}

__global__ __launch_bounds__(NT)
void cky_fused_kernel(const float* __restrict__ scores,
                      const int* __restrict__ cpos,
                      float* __restrict__ ws)
{
    __shared__ float2 chart[NCELLS];        // .x = pred, .y = constr
    __shared__ float  sbuf[2][SBUF];        // double-buffered staged scores

    const int b   = blockIdx.x;
    const int tid = threadIdx.x;
    const float* __restrict__ g = scores + (size_t)b * TOTAL;
    float* __restrict__ sb0 = &sbuf[0][0];
    float* __restrict__ sb1 = &sbuf[1][0];

    // ---- stage level-1 scores (127 floats) into parity-1 buffer ----
    stage(g, 0, 127, sb1, tid);

    int cp = 0;
    if (tid < NCONSTR) cp = cpos[b * NCONSTR + tid];

    // ---- init both charts ----
    for (int i = tid; i < NCELLS; i += NT) chart[i] = make_float2(0.f, 0.f);
    drain_barrier();                        // staging + init complete
    if (tid < NCONSTR) chart[cp].y = BONUS; // set (not add); duplicates benign
    level_barrier();

    int soff = 0;

    // ---- TPP=4: levels 1..60 via exact-JM segments ----
    seg4<1>(soff, g, chart, sb0, sb1, tid);
    seg4<2>(soff, g, chart, sb0, sb1, tid);
    seg4<3>(soff, g, chart, sb0, sb1, tid);
    seg4<4>(soff, g, chart, sb0, sb1, tid);
    seg4<5>(soff, g, chart, sb0, sb1, tid);
    seg4<6>(soff, g, chart, sb0, sb1, tid);
    seg4<7>(soff, g, chart, sb0, sb1, tid);
    seg4<8>(soff, g, chart, sb0, sb1, tid);
    seg4<9>(soff, g, chart, sb0, sb1, tid);
    seg4<10>(soff, g, chart, sb0, sb1, tid);
    seg4<11>(soff, g, chart, sb0, sb1, tid);
    seg4<12>(soff, g, chart, sb0, sb1, tid);
    seg4<13>(soff, g, chart, sb0, sb1, tid);
    seg4<14>(soff, g, chart, sb0, sb1, tid);
    seg4<15>(soff, g, chart, sb0, sb1, tid);
    // ---- TPP=4 tail: levels 61..63 ----
    lstep<2,16,true>(61, soff, g, chart, sb1, sb0, tid);
    lstep<2,16,true>(62, soff, g, chart, sb0, sb1, tid);
    lstep<2,16,true>(63, soff, g, chart, sb1, sb0, tid);
    // ---- TPP=8: levels 64..95 ----
    lstep<3,8,true> (64, soff, g, chart, sb0, sb1, tid);
    #pragma unroll 1
    for (int l = 65; l < 72; l += 2) {                   // 65..72 (JM=9)
        lstep<3,9,true>(l,     soff, g, chart, sb1, sb0, tid);
        lstep<3,9,true>(l + 1, soff, g, chart, sb0, sb1, tid);
    }
    #pragma unroll 1
    for (int l = 73; l < 80; l += 2) {                   // 73..80 (JM=10)
        lstep<3,10,true>(l,     soff, g, chart, sb1, sb0, tid);
        lstep<3,10,true>(l + 1, soff, g, chart, sb0, sb1, tid);
    }
    #pragma unroll 1
    for (int l = 81; l < 88; l += 2) {                   // 81..88 (JM=11)
        lstep<3,11,true>(l,     soff, g, chart, sb1, sb0, tid);
        lstep<3,11,true>(l + 1, soff, g, chart, sb0, sb1, tid);
    }
    #pragma unroll 1
    for (int l = 89; l < 94; l += 2) {                   // 89..94 (JM=12)
        lstep<3,12,true>(l,     soff, g, chart, sb1, sb0, tid);
        lstep<3,12,true>(l + 1, soff, g, chart, sb0, sb1, tid);
    }
    lstep<3,12,true>(95, soff, g, chart, sb1, sb0, tid);
    // ---- TPP=16: levels 96..111 ----
    lstep<4,6,true> (96, soff, g, chart, sb0, sb1, tid);
    #pragma unroll 1
    for (int l = 97; l < 110; l += 2) {                  // 97..110 (JM=7)
        lstep<4,7,true>(l,     soff, g, chart, sb1, sb0, tid);
        lstep<4,7,true>(l + 1, soff, g, chart, sb0, sb1, tid);
    }
    lstep<4,7,true>(111, soff, g, chart, sb1, sb0, tid);
    // ---- TPP=32: levels 112..119 ----
    lstep<5,4,true>(112, soff, g, chart, sb0, sb1, tid);
    #pragma unroll 1
    for (int l = 113; l < 118; l += 2) {                 // 113..118
        lstep<5,4,true>(l,     soff, g, chart, sb1, sb0, tid);
        lstep<5,4,true>(l + 1, soff, g, chart, sb0, sb1, tid);
    }
    lstep<5,4,true>(119, soff, g, chart, sb1, sb0, tid);
    // ---- TPP=64: levels 120..127 ----
    lstep<6,2,true>(120, soff, g, chart, sb0, sb1, tid);
    #pragma unroll 1
    for (int l = 121; l < 126; l += 2) {                 // 121..126
        lstep<6,2,true>(l,     soff, g, chart, sb1, sb0, tid);
        lstep<6,2,true>(l + 1, soff, g, chart, sb0, sb1, tid);
    }
    lstep<6,2,false>(127, soff, g, chart, sb1, sb0, tid); // root; no staging

    // ---- per-batch hinge contribution ----
    if (tid == 0) {
        const float2 f = chart[NCELLS - 1];
        const float pred   = f.x;
        const float constr = f.y - BONUS * NCONSTR;
        const float diff   = pred - constr;
        const float mask   = (fabsf(diff) >= 0.001f) ? 1.f : 0.f;
        const float hinge  = fmaxf(1.0f + diff, 0.f) * mask;
        atomicAdd(ws + 0, hinge);
        atomicAdd(ws + 1, mask);
    }
}

__global__ void final_kernel(const float* __restrict__ ws, float* __restrict__ out) {
    const float h = ws[0];
    const float m = ws[1];
    out[0] = (m > 0.1f) ? (h / fmaxf(m, 1.f)) : h;
}

extern "C" void kernel_launch(void* const* d_in, const int* in_sizes, int n_in,
                              void* d_out, int out_size, void* d_ws, size_t ws_size,
                              hipStream_t stream) {
    const float* scores = (const float*)d_in[0];
    const int*   cpos   = (const int*)d_in[1];
    float* out = (float*)d_out;
    float* ws  = (float*)d_ws;

    hipMemsetAsync(ws, 0, 2 * sizeof(float), stream);
    cky_fused_kernel<<<dim3(256), dim3(NT), 0, stream>>>(scores, cpos, ws);
    final_kernel<<<dim3(1), dim3(1), 0, stream>>>(ws, out);
}